// Round 2
// baseline (2723.882 us; speedup 1.0000x reference)
//
#include <hip/hip_runtime.h>

#define HID 128
#define NLAY 4

__device__ __forceinline__ float silu_f(float x) {
  return x / (1.0f + __expf(-x));
}

__device__ __forceinline__ void dot4(float& acc, const float4& u, const float4& wv) {
  acc = fmaf(u.x, wv.x, fmaf(u.y, wv.y, fmaf(u.z, wv.z, fmaf(u.w, wv.w, acc))));
}

// ---------------- conditioning: h table (B=8 x 128) ----------------
__global__ void hb_kernel(const float* __restrict__ t, const float* __restrict__ z,
                          const float* __restrict__ te_w1, const float* __restrict__ te_b1,
                          const float* __restrict__ te_w2, const float* __restrict__ te_b2,
                          const float* __restrict__ cp_w, const float* __restrict__ cp_b,
                          float* __restrict__ hb) {
  int b = blockIdx.x;      // 0..7
  int j = threadIdx.x;     // 0..127
  float tv = t[b];
  float e1[16];
  #pragma unroll
  for (int i = 0; i < 16; ++i) e1[i] = silu_f(tv * te_w1[i] + te_b1[i]);
  float acc = cp_b[j];
  for (int i = 0; i < 64; ++i) acc += z[b*64 + i] * cp_w[i*HID + j];
  #pragma unroll
  for (int i = 0; i < 16; ++i) {
    float te = te_b2[i];
    #pragma unroll
    for (int k = 0; k < 16; ++k) te += e1[k] * te_w2[k*16 + i];
    acc += te * cp_w[(64 + i)*HID + j];
  }
  hb[b*HID + j] = acc;
}

__global__ void scatter_h_kernel(const int* __restrict__ batch, const float* __restrict__ hb,
                                 float* __restrict__ h, int V) {
  int idx = blockIdx.x * blockDim.x + threadIdx.x;
  if (idx < V * 32) {
    int v = idx >> 5, c = idx & 31;
    int b = batch[v];
    ((float4*)h)[(size_t)v*32 + c] = ((const float4*)hb)[b*32 + c];
  }
}

__global__ void packx_kernel(const float* __restrict__ pos, float4* __restrict__ x4, int V) {
  int v = blockIdx.x * blockDim.x + threadIdx.x;
  if (v < V) x4[v] = make_float4(pos[3*v], pos[3*v+1], pos[3*v+2], 0.f);
}

// ---------------- CSR build (counting sort by row) ----------------
__global__ void hist_kernel(const int* __restrict__ rowp, int* __restrict__ cnt, int E) {
  int e = blockIdx.x * blockDim.x + threadIdx.x;
  if (e < E) atomicAdd(&cnt[rowp[e]], 1);
}

__global__ void scan_kernel(const int* __restrict__ cnt, int* __restrict__ offp, int V) {
  __shared__ int s[1024];
  __shared__ int carry_s;
  int tid = threadIdx.x;
  if (tid == 0) carry_s = 0;
  __syncthreads();
  for (int base = 0; base < V; base += 1024) {
    int v = base + tid;
    int val = (v < V) ? cnt[v] : 0;
    s[tid] = val;
    __syncthreads();
    for (int d = 1; d < 1024; d <<= 1) {
      int tval = (tid >= d) ? s[tid - d] : 0;
      __syncthreads();
      s[tid] += tval;
      __syncthreads();
    }
    int c0 = carry_s;
    if (v < V) offp[v] = c0 + s[tid] - val;   // exclusive
    int tot = s[1023];
    __syncthreads();
    if (tid == 0) carry_s = c0 + tot;
    __syncthreads();
  }
  if (tid == 0) offp[V] = carry_s;
}

__global__ void scatter_perm_kernel(const int* __restrict__ rowp, const int* __restrict__ offp,
                                    int* __restrict__ fill, int* __restrict__ perm, int E) {
  int e = blockIdx.x * blockDim.x + threadIdx.x;
  if (e < E) {
    int r = rowp[e];
    int p = offp[r] + atomicAdd(&fill[r], 1);
    perm[p] = e;
  }
}

// ---------------- p_kernel: p1 = h@We1[0:128], p2 = h@We1[128:256] ----------------
// LDS: W transposed+swizzled [o=256][k=128], + per-wave U. 147456 B.
__global__ __launch_bounds__(1024) void p_kernel(
    const float* __restrict__ h, const float* __restrict__ We1_l,
    float* __restrict__ p1, float* __restrict__ p2, int V)
{
  extern __shared__ float lds[];
  float* ldsW = lds;               // 256*128
  float* ldsU = lds + 256*128;     // 16 waves * 256
  int tid = threadIdx.x;
  for (int i4 = tid; i4 < 8192; i4 += 1024) {
    float4 wv = ((const float4*)We1_l)[i4];
    int flat = i4 << 2;
    int r = flat >> 7;
    int c = flat & 127;
    int k = r & 127;
    int ob = (r < 128) ? c : (128 + c);
    const float* pv = (const float*)&wv;
    #pragma unroll
    for (int q = 0; q < 4; ++q) {
      int o = ob + q;
      ldsW[o*128 + (k ^ ((o & 7) << 2))] = pv[q];
    }
  }
  __syncthreads();
  const int wave = tid >> 6, lane = tid & 63;
  float* myU = ldsU + wave*256;
  const int sw = (lane & 7) << 2;
  const int gw = blockIdx.x*16 + wave;
  const int nw = gridDim.x*16;
  const int ntiles = V >> 1;
  for (int tt = gw; tt < ntiles; tt += nw) {
    int v0 = 2*tt, v1 = v0 + 1;
    myU[lane]      = h[(size_t)v0*HID + lane];
    myU[lane+64]   = h[(size_t)v0*HID + lane + 64];
    myU[128+lane]  = h[(size_t)v1*HID + lane];
    myU[192+lane]  = h[(size_t)v1*HID + lane + 64];
    float a00=0.f,a01=0.f,a02=0.f,a03=0.f,a10=0.f,a11=0.f,a12=0.f,a13=0.f;
    #pragma unroll 8
    for (int k0 = 0; k0 < 128; k0 += 4) {
      int kk = k0 ^ sw;
      float4 w0 = *(const float4*)&ldsW[(lane      )*128 + kk];
      float4 w1 = *(const float4*)&ldsW[(lane +  64)*128 + kk];
      float4 w2 = *(const float4*)&ldsW[(lane + 128)*128 + kk];
      float4 w3 = *(const float4*)&ldsW[(lane + 192)*128 + kk];
      float4 u0 = *(const float4*)&myU[k0];
      float4 u1 = *(const float4*)&myU[128 + k0];
      dot4(a00,u0,w0); dot4(a01,u0,w1); dot4(a02,u0,w2); dot4(a03,u0,w3);
      dot4(a10,u1,w0); dot4(a11,u1,w1); dot4(a12,u1,w2); dot4(a13,u1,w3);
    }
    p1[(size_t)v0*HID + lane]      = a00;
    p1[(size_t)v0*HID + lane + 64] = a01;
    p2[(size_t)v0*HID + lane]      = a02;
    p2[(size_t)v0*HID + lane + 64] = a03;
    p1[(size_t)v1*HID + lane]      = a10;
    p1[(size_t)v1*HID + lane + 64] = a11;
    p2[(size_t)v1*HID + lane]      = a12;
    p2[(size_t)v1*HID + lane + 64] = a13;
  }
}

// ---------------- edge kernel: fused edge MLP ----------------
// LDS: We2T swz (64KB) + Wc1T swz (64KB) + per-wave U (16KB) = 147456 B.
__global__ __launch_bounds__(1024) void edge_kernel(
    const int* __restrict__ rowp, const int* __restrict__ colp,
    const float4* __restrict__ x4,
    const float* __restrict__ p1, const float* __restrict__ p2,
    const float* __restrict__ We2_l, const float* __restrict__ Wc1_l,
    const float* __restrict__ Wc2_l, const float* __restrict__ wd2_l,
    const float* __restrict__ be1_l, const float* __restrict__ be2_l,
    const float* __restrict__ bc1_l,
    float* __restrict__ m_ws, float4* __restrict__ rc_ws, int E)
{
  extern __shared__ float lds[];
  float* ldsW2 = lds;
  float* ldsC1 = lds + 16384;
  float* ldsU  = lds + 32768;
  int tid = threadIdx.x;
  for (int i4 = tid; i4 < 4096; i4 += 1024) {
    float4 wa = ((const float4*)We2_l)[i4];
    float4 wb = ((const float4*)Wc1_l)[i4];
    int flat = i4 << 2;
    int k = flat >> 7;
    int c = flat & 127;
    const float* pa = (const float*)&wa;
    const float* pb = (const float*)&wb;
    #pragma unroll
    for (int q = 0; q < 4; ++q) {
      int o = c + q;
      int pidx = o*128 + (k ^ ((o & 7) << 2));
      ldsW2[pidx] = pa[q];
      ldsC1[pidx] = pb[q];
    }
  }
  __syncthreads();
  const int wave = tid >> 6, lane = tid & 63;
  float* myU = ldsU + wave*256;
  const int sw = (lane & 7) << 2;
  const float wd2a = wd2_l[lane], wd2b = wd2_l[lane+64];
  const float be1a = be1_l[lane], be1b = be1_l[lane+64];
  const float be2a = be2_l[lane], be2b = be2_l[lane+64];
  const float bc1a = bc1_l[lane], bc1b = bc1_l[lane+64];
  const float wc2a = Wc2_l[lane], wc2b = Wc2_l[lane+64];
  const int gw = blockIdx.x*16 + wave;
  const int nw = gridDim.x*16;
  const int ntiles = E >> 1;
  for (int tt = gw; tt < ntiles; tt += nw) {
    int e0 = 2*tt, e1 = e0 + 1;
    int r0 = rowp[e0], c0 = colp[e0], r1 = rowp[e1], c1 = colp[e1];
    float4 xr0 = x4[r0], xc0 = x4[c0], xr1 = x4[r1], xc1 = x4[c1];
    float dx0 = xr0.x-xc0.x, dy0 = xr0.y-xc0.y, dz0 = xr0.z-xc0.z;
    float dx1 = xr1.x-xc1.x, dy1 = xr1.y-xc1.y, dz1 = xr1.z-xc1.z;
    float d20 = dx0*dx0 + dy0*dy0 + dz0*dz0;
    float d21 = dx1*dx1 + dy1*dy1 + dz1*dz1;
    float u0a = silu_f(p1[(size_t)r0*HID+lane]    + p2[(size_t)c0*HID+lane]    + d20*wd2a + be1a);
    float u0b = silu_f(p1[(size_t)r0*HID+lane+64] + p2[(size_t)c0*HID+lane+64] + d20*wd2b + be1b);
    float u1a = silu_f(p1[(size_t)r1*HID+lane]    + p2[(size_t)c1*HID+lane]    + d21*wd2a + be1a);
    float u1b = silu_f(p1[(size_t)r1*HID+lane+64] + p2[(size_t)c1*HID+lane+64] + d21*wd2b + be1b);
    myU[lane] = u0a; myU[lane+64] = u0b;
    myU[128+lane] = u1a; myU[192+lane] = u1b;
    float m0a=0.f,m0b=0.f,m1a=0.f,m1b=0.f;
    #pragma unroll 8
    for (int k0 = 0; k0 < 128; k0 += 4) {
      int kk = k0 ^ sw;
      float4 wA = *(const float4*)&ldsW2[lane*128 + kk];
      float4 wB = *(const float4*)&ldsW2[(lane+64)*128 + kk];
      float4 u0 = *(const float4*)&myU[k0];
      float4 u1 = *(const float4*)&myU[128+k0];
      dot4(m0a,u0,wA); dot4(m0b,u0,wB); dot4(m1a,u1,wA); dot4(m1b,u1,wB);
    }
    m0a = silu_f(m0a + be2a); m0b = silu_f(m0b + be2b);
    m1a = silu_f(m1a + be2a); m1b = silu_f(m1b + be2b);
    m_ws[(size_t)e0*HID + lane]    = m0a;
    m_ws[(size_t)e0*HID + lane+64] = m0b;
    m_ws[(size_t)e1*HID + lane]    = m1a;
    m_ws[(size_t)e1*HID + lane+64] = m1b;
    myU[lane] = m0a; myU[lane+64] = m0b;
    myU[128+lane] = m1a; myU[192+lane] = m1b;
    float t0a=0.f,t0b=0.f,t1a=0.f,t1b=0.f;
    #pragma unroll 8
    for (int k0 = 0; k0 < 128; k0 += 4) {
      int kk = k0 ^ sw;
      float4 wA = *(const float4*)&ldsC1[lane*128 + kk];
      float4 wB = *(const float4*)&ldsC1[(lane+64)*128 + kk];
      float4 u0 = *(const float4*)&myU[k0];
      float4 u1 = *(const float4*)&myU[128+k0];
      dot4(t0a,u0,wA); dot4(t0b,u0,wB); dot4(t1a,u1,wA); dot4(t1b,u1,wB);
    }
    t0a = silu_f(t0a + bc1a); t0b = silu_f(t0b + bc1b);
    t1a = silu_f(t1a + bc1a); t1b = silu_f(t1b + bc1b);
    float pt0 = t0a*wc2a + t0b*wc2b;
    float pt1 = t1a*wc2a + t1b*wc2b;
    #pragma unroll
    for (int o = 32; o > 0; o >>= 1) {
      pt0 += __shfl_down(pt0, o);
      pt1 += __shfl_down(pt1, o);
    }
    if (lane == 0) {
      rc_ws[e0] = make_float4(dx0*pt0, dy0*pt0, dz0*pt0, 0.f);
      rc_ws[e1] = make_float4(dx1*pt1, dy1*pt1, dz1*pt1, 0.f);
    }
  }
}

// ---------------- aggregation: agg[v] = sum m, x[v] += sum rel*coef ----------------
__global__ void agg_kernel(const int* __restrict__ offp, const int* __restrict__ perm,
                           const float* __restrict__ m_ws, const float4* __restrict__ rc_ws,
                           float* __restrict__ agg, float4* __restrict__ x4, int V)
{
  int wave = threadIdx.x >> 6, lane = threadIdx.x & 63;
  int v = blockIdx.x*4 + wave;
  if (v >= V) return;
  int s = offp[v], e = offp[v+1];
  float acc0 = 0.f, acc1 = 0.f;
  float rx = 0.f, ry = 0.f, rz = 0.f;
  for (int i = s; i < e; ++i) {
    int ed = perm[i];
    float2 mv = ((const float2*)m_ws)[(size_t)ed*64 + lane];
    acc0 += mv.x; acc1 += mv.y;
    float4 rc = rc_ws[ed];
    rx += rc.x; ry += rc.y; rz += rc.z;
  }
  ((float2*)agg)[(size_t)v*64 + lane] = make_float2(acc0, acc1);
  if (lane == 0) {
    float4 xv = x4[v];
    xv.x += rx; xv.y += ry; xv.z += rz;
    x4[v] = xv;
  }
}

// ---------------- node update 1: q = silu([h,agg]@Wn1 + bn1) ----------------
__global__ __launch_bounds__(1024) void nu1_kernel(
    const float* __restrict__ h, const float* __restrict__ agg,
    const float* __restrict__ Wn1_l, const float* __restrict__ bn1_l,
    float* __restrict__ q, int V)
{
  extern __shared__ float lds[];
  float* ldsW = lds;               // [o=128][k=256] swz
  float* ldsU = lds + 128*256;
  int tid = threadIdx.x;
  for (int i4 = tid; i4 < 8192; i4 += 1024) {
    float4 wv = ((const float4*)Wn1_l)[i4];
    int flat = i4 << 2;
    int r = flat >> 7;       // k (0..255)
    int c = flat & 127;
    const float* pv = (const float*)&wv;
    #pragma unroll
    for (int qq = 0; qq < 4; ++qq) {
      int o = c + qq;
      ldsW[o*256 + (r ^ ((o & 7) << 2))] = pv[qq];
    }
  }
  __syncthreads();
  const int wave = tid >> 6, lane = tid & 63;
  float* myU = ldsU + wave*256;
  const int sw = (lane & 7) << 2;
  const float b_a = bn1_l[lane], b_b = bn1_l[lane+64];
  const int gw = blockIdx.x*16 + wave;
  const int nw = gridDim.x*16;
  for (int v = gw; v < V; v += nw) {
    myU[lane]     = h[(size_t)v*HID + lane];
    myU[lane+64]  = h[(size_t)v*HID + lane+64];
    myU[128+lane] = agg[(size_t)v*HID + lane];
    myU[192+lane] = agg[(size_t)v*HID + lane+64];
    float aa = 0.f, ab = 0.f;
    #pragma unroll 8
    for (int k0 = 0; k0 < 256; k0 += 4) {
      int kk = k0 ^ sw;
      float4 wA = *(const float4*)&ldsW[lane*256 + kk];
      float4 wB = *(const float4*)&ldsW[(lane+64)*256 + kk];
      float4 uu = *(const float4*)&myU[k0];
      dot4(aa, uu, wA); dot4(ab, uu, wB);
    }
    q[(size_t)v*HID + lane]    = silu_f(aa + b_a);
    q[(size_t)v*HID + lane+64] = silu_f(ab + b_b);
  }
}

// ---------------- node update 2: h += q@Wn2 + bn2 ----------------
__global__ __launch_bounds__(1024) void nu2_kernel(
    const float* __restrict__ q, const float* __restrict__ Wn2_l,
    const float* __restrict__ bn2_l, float* __restrict__ h, int V)
{
  extern __shared__ float lds[];
  float* ldsW = lds;               // [128][128] swz
  float* ldsU = lds + 128*128;
  int tid = threadIdx.x;
  for (int i4 = tid; i4 < 4096; i4 += 1024) {
    float4 wv = ((const float4*)Wn2_l)[i4];
    int flat = i4 << 2;
    int k = flat >> 7;
    int c = flat & 127;
    const float* pv = (const float*)&wv;
    #pragma unroll
    for (int qq = 0; qq < 4; ++qq) {
      int o = c + qq;
      ldsW[o*128 + (k ^ ((o & 7) << 2))] = pv[qq];
    }
  }
  __syncthreads();
  const int wave = tid >> 6, lane = tid & 63;
  float* myU = ldsU + wave*256;
  const int sw = (lane & 7) << 2;
  const float b_a = bn2_l[lane], b_b = bn2_l[lane+64];
  const int gw = blockIdx.x*16 + wave;
  const int nw = gridDim.x*16;
  const int ntiles = V >> 1;
  for (int tt = gw; tt < ntiles; tt += nw) {
    int v0 = 2*tt, v1 = v0 + 1;
    myU[lane]     = q[(size_t)v0*HID + lane];
    myU[lane+64]  = q[(size_t)v0*HID + lane+64];
    myU[128+lane] = q[(size_t)v1*HID + lane];
    myU[192+lane] = q[(size_t)v1*HID + lane+64];
    float a0a=0.f,a0b=0.f,a1a=0.f,a1b=0.f;
    #pragma unroll 8
    for (int k0 = 0; k0 < 128; k0 += 4) {
      int kk = k0 ^ sw;
      float4 wA = *(const float4*)&ldsW[lane*128 + kk];
      float4 wB = *(const float4*)&ldsW[(lane+64)*128 + kk];
      float4 u0 = *(const float4*)&myU[k0];
      float4 u1 = *(const float4*)&myU[128+k0];
      dot4(a0a,u0,wA); dot4(a0b,u0,wB); dot4(a1a,u1,wA); dot4(a1b,u1,wB);
    }
    h[(size_t)v0*HID+lane]    += a0a + b_a;
    h[(size_t)v0*HID+lane+64] += a0b + b_b;
    h[(size_t)v1*HID+lane]    += a1a + b_a;
    h[(size_t)v1*HID+lane+64] += a1b + b_b;
  }
}

__global__ void vel_kernel(const float4* __restrict__ x4, const float* __restrict__ pos,
                           float* __restrict__ out, int V) {
  int v = blockIdx.x * blockDim.x + threadIdx.x;
  if (v < V) {
    float4 xv = x4[v];
    out[3*v]   = xv.x - pos[3*v];
    out[3*v+1] = xv.y - pos[3*v+1];
    out[3*v+2] = xv.z - pos[3*v+2];
  }
}

extern "C" void kernel_launch(void* const* d_in, const int* in_sizes, int n_in,
                              void* d_out, int out_size, void* d_ws, size_t ws_size,
                              hipStream_t stream) {
  const float* pos   = (const float*)d_in[0];
  const float* t     = (const float*)d_in[1];
  const float* z     = (const float*)d_in[2];
  const int*   ei    = (const int*)d_in[3];
  const int*   batch = (const int*)d_in[4];
  const float* te_w1 = (const float*)d_in[5];
  const float* te_b1 = (const float*)d_in[6];
  const float* te_w2 = (const float*)d_in[7];
  const float* te_b2 = (const float*)d_in[8];
  const float* cp_w  = (const float*)d_in[9];
  const float* cp_b  = (const float*)d_in[10];
  const float* We1   = (const float*)d_in[11];
  const float* be1   = (const float*)d_in[12];
  const float* We2   = (const float*)d_in[13];
  const float* be2   = (const float*)d_in[14];
  const float* Wc1   = (const float*)d_in[15];
  const float* bc1   = (const float*)d_in[16];
  const float* Wc2   = (const float*)d_in[17];
  const float* Wn1   = (const float*)d_in[18];
  const float* bn1   = (const float*)d_in[19];
  const float* Wn2   = (const float*)d_in[20];
  const float* bn2   = (const float*)d_in[21];

  const int V = in_sizes[4];
  const int E = in_sizes[3] / 2;
  const int* rowp = ei;
  const int* colp = ei + E;

  char* base = (char*)d_ws;
  size_t off_b = 0;
  auto alloc = [&](size_t bytes) -> char* {
    char* p = base + off_b;
    off_b += (bytes + 255) & ~(size_t)255;
    return p;
  };
  float*  h     = (float*) alloc((size_t)V*HID*4);
  float*  pA    = (float*) alloc((size_t)V*HID*4);   // p1, later q
  float*  pB    = (float*) alloc((size_t)V*HID*4);   // p2, later agg
  float4* x4    = (float4*)alloc((size_t)V*16);
  float*  m_ws  = (float*) alloc((size_t)E*HID*4);
  float4* rc_ws = (float4*)alloc((size_t)E*16);
  float*  hb    = (float*) alloc(8*HID*4);
  int*    cnt   = (int*)   alloc((size_t)V*4);
  int*    offp  = (int*)   alloc((size_t)(V+1)*4);
  int*    fill  = (int*)   alloc((size_t)V*4);
  int*    perm  = (int*)   alloc((size_t)E*4);
  (void)ws_size; (void)n_in; (void)out_size;

  hipFuncSetAttribute((const void*)p_kernel,    hipFuncAttributeMaxDynamicSharedMemorySize, 147456);
  hipFuncSetAttribute((const void*)edge_kernel, hipFuncAttributeMaxDynamicSharedMemorySize, 147456);
  hipFuncSetAttribute((const void*)nu1_kernel,  hipFuncAttributeMaxDynamicSharedMemorySize, 147456);
  hipFuncSetAttribute((const void*)nu2_kernel,  hipFuncAttributeMaxDynamicSharedMemorySize, 81920);

  hb_kernel<<<8, 128, 0, stream>>>(t, z, te_w1, te_b1, te_w2, te_b2, cp_w, cp_b, hb);
  scatter_h_kernel<<<(V*32 + 255)/256, 256, 0, stream>>>(batch, hb, h, V);
  packx_kernel<<<(V + 255)/256, 256, 0, stream>>>(pos, x4, V);
  hipMemsetAsync(cnt, 0, (size_t)V*4, stream);
  hipMemsetAsync(fill, 0, (size_t)V*4, stream);
  hist_kernel<<<(E + 255)/256, 256, 0, stream>>>(rowp, cnt, E);
  scan_kernel<<<1, 1024, 0, stream>>>(cnt, offp, V);
  scatter_perm_kernel<<<(E + 255)/256, 256, 0, stream>>>(rowp, offp, fill, perm, E);

  for (int l = 0; l < NLAY; ++l) {
    const float* We1_l = We1 + (size_t)l*257*HID;
    const float* wd2_l = We1_l + 256*HID;        // We1[l][256][:]
    const float* We2_l = We2 + (size_t)l*HID*HID;
    const float* Wc1_l = Wc1 + (size_t)l*HID*HID;
    const float* Wc2_l = Wc2 + (size_t)l*HID;
    const float* Wn1_l = Wn1 + (size_t)l*256*HID;
    const float* Wn2_l = Wn2 + (size_t)l*HID*HID;
    const float* be1_l = be1 + l*HID;
    const float* be2_l = be2 + l*HID;
    const float* bc1_l = bc1 + l*HID;
    const float* bn1_l = bn1 + l*HID;
    const float* bn2_l = bn2 + l*HID;

    p_kernel<<<256, 1024, 147456, stream>>>(h, We1_l, pA, pB, V);
    edge_kernel<<<256, 1024, 147456, stream>>>(rowp, colp, x4, pA, pB,
                                               We2_l, Wc1_l, Wc2_l, wd2_l,
                                               be1_l, be2_l, bc1_l, m_ws, rc_ws, E);
    agg_kernel<<<(V + 3)/4, 256, 0, stream>>>(offp, perm, m_ws, rc_ws, pB, x4, V);
    nu1_kernel<<<256, 1024, 147456, stream>>>(h, pB, Wn1_l, bn1_l, pA, V);
    nu2_kernel<<<512, 1024, 81920, stream>>>(pA, Wn2_l, bn2_l, h, V);
  }
  vel_kernel<<<(V + 255)/256, 256, 0, stream>>>(x4, pos, (float*)d_out, V);
}

// Round 3
// 2553.474 us; speedup vs baseline: 1.0667x; 1.0667x over previous
//
#include <hip/hip_runtime.h>

#define HID 128
#define NLAY 4

__device__ __forceinline__ float silu_f(float x) {
  return x / (1.0f + __expf(-x));
}

__device__ __forceinline__ void dot4(float& acc, const float4& u, const float4& wv) {
  acc = fmaf(u.x, wv.x, fmaf(u.y, wv.y, fmaf(u.z, wv.z, fmaf(u.w, wv.w, acc))));
}

// Stage a [128][128] row-major W (W[k][o]) into LDS transposed+swizzled:
// ldsW[o*128 + (k ^ ((o&7)<<2))] = W[k][o]
__device__ __forceinline__ void stage_w128(const float* __restrict__ W, float* ldsW, int tid) {
  for (int i4 = tid; i4 < 4096; i4 += 1024) {
    float4 wv = ((const float4*)W)[i4];
    int flat = i4 << 2;
    int k = flat >> 7;
    int c = flat & 127;
    const float* pv = (const float*)&wv;
    #pragma unroll
    for (int q = 0; q < 4; ++q) {
      int o = c + q;
      ldsW[o*128 + (k ^ ((o & 7) << 2))] = pv[q];
    }
  }
}

// ---------------- conditioning: h table (B=8 x 128) ----------------
__global__ void hb_kernel(const float* __restrict__ t, const float* __restrict__ z,
                          const float* __restrict__ te_w1, const float* __restrict__ te_b1,
                          const float* __restrict__ te_w2, const float* __restrict__ te_b2,
                          const float* __restrict__ cp_w, const float* __restrict__ cp_b,
                          float* __restrict__ hb) {
  int b = blockIdx.x;      // 0..7
  int j = threadIdx.x;     // 0..127
  float tv = t[b];
  float e1[16];
  #pragma unroll
  for (int i = 0; i < 16; ++i) e1[i] = silu_f(tv * te_w1[i] + te_b1[i]);
  float acc = cp_b[j];
  for (int i = 0; i < 64; ++i) acc += z[b*64 + i] * cp_w[i*HID + j];
  #pragma unroll
  for (int i = 0; i < 16; ++i) {
    float te = te_b2[i];
    #pragma unroll
    for (int k = 0; k < 16; ++k) te += e1[k] * te_w2[k*16 + i];
    acc += te * cp_w[(64 + i)*HID + j];
  }
  hb[b*HID + j] = acc;
}

__global__ void scatter_h_kernel(const int* __restrict__ batch, const float* __restrict__ hb,
                                 float* __restrict__ h, int V) {
  int idx = blockIdx.x * blockDim.x + threadIdx.x;
  if (idx < V * 32) {
    int v = idx >> 5, c = idx & 31;
    int b = batch[v];
    ((float4*)h)[(size_t)v*32 + c] = ((const float4*)hb)[b*32 + c];
  }
}

__global__ void packx_kernel(const float* __restrict__ pos, float4* __restrict__ x4, int V) {
  int v = blockIdx.x * blockDim.x + threadIdx.x;
  if (v < V) x4[v] = make_float4(pos[3*v], pos[3*v+1], pos[3*v+2], 0.f);
}

// ---------------- CSR build (counting sort by row) ----------------
__global__ void hist_kernel(const int* __restrict__ rowp, int* __restrict__ cnt, int E) {
  int e = blockIdx.x * blockDim.x + threadIdx.x;
  if (e < E) atomicAdd(&cnt[rowp[e]], 1);
}

__global__ void scan_kernel(const int* __restrict__ cnt, int* __restrict__ offp, int V) {
  __shared__ int s[1024];
  __shared__ int carry_s;
  int tid = threadIdx.x;
  if (tid == 0) carry_s = 0;
  __syncthreads();
  for (int base = 0; base < V; base += 1024) {
    int v = base + tid;
    int val = (v < V) ? cnt[v] : 0;
    s[tid] = val;
    __syncthreads();
    for (int d = 1; d < 1024; d <<= 1) {
      int tval = (tid >= d) ? s[tid - d] : 0;
      __syncthreads();
      s[tid] += tval;
      __syncthreads();
    }
    int c0 = carry_s;
    if (v < V) offp[v] = c0 + s[tid] - val;   // exclusive
    int tot = s[1023];
    __syncthreads();
    if (tid == 0) carry_s = c0 + tot;
    __syncthreads();
  }
  if (tid == 0) offp[V] = carry_s;
}

__global__ void scatter_perm_kernel(const int* __restrict__ rowp, const int* __restrict__ offp,
                                    int* __restrict__ fill, int* __restrict__ perm, int E) {
  int e = blockIdx.x * blockDim.x + threadIdx.x;
  if (e < E) {
    int r = rowp[e];
    int p = offp[r] + atomicAdd(&fill[r], 1);
    perm[p] = e;
  }
}

// ---------------- phalf: pout[v][:] = h[v][:] @ W128 (no bias) ----------------
// 8 nodes per wave; LDS = W 64KB + 16 waves * 8 * 128 floats U = 128KB.
__global__ __launch_bounds__(1024, 4) void phalf_kernel(
    const float* __restrict__ h, const float* __restrict__ W128,
    float* __restrict__ pout, int V)
{
  extern __shared__ float lds[];
  float* ldsW = lds;
  float* ldsU = lds + 16384;
  int tid = threadIdx.x;
  stage_w128(W128, ldsW, tid);
  __syncthreads();
  const int wave = tid >> 6, lane = tid & 63;
  float* myU = ldsU + wave*1024;
  const int sw = (lane & 7) << 2;
  const int gw = blockIdx.x*16 + wave;
  const int nw = gridDim.x*16;
  const int ntiles = V >> 3;
  for (int tt = gw; tt < ntiles; tt += nw) {
    int vb = tt << 3;
    #pragma unroll
    for (int n = 0; n < 8; ++n) {
      myU[n*128 + lane]      = h[(size_t)(vb+n)*HID + lane];
      myU[n*128 + lane + 64] = h[(size_t)(vb+n)*HID + lane + 64];
    }
    float aa[8], ab[8];
    #pragma unroll
    for (int n = 0; n < 8; ++n) { aa[n] = 0.f; ab[n] = 0.f; }
    #pragma unroll 8
    for (int k0 = 0; k0 < 128; k0 += 4) {
      int kk = k0 ^ sw;
      float4 wA = *(const float4*)&ldsW[lane*128 + kk];
      float4 wB = *(const float4*)&ldsW[(lane+64)*128 + kk];
      #pragma unroll
      for (int n = 0; n < 8; ++n) {
        float4 u = *(const float4*)&myU[n*128 + k0];
        dot4(aa[n], u, wA); dot4(ab[n], u, wB);
      }
    }
    #pragma unroll
    for (int n = 0; n < 8; ++n) {
      pout[(size_t)(vb+n)*HID + lane]      = aa[n];
      pout[(size_t)(vb+n)*HID + lane + 64] = ab[n];
    }
  }
}

// ---------------- edge1: u = silu(p1[r]+p2[c]+d2*wd2+be1); m = silu(u@We2+be2) ----------------
// also stashes rel in rc_ws. LDS = We2 64KB + U 64KB.
__global__ __launch_bounds__(1024, 4) void edge1_kernel(
    const int* __restrict__ rowp, const int* __restrict__ colp,
    const float4* __restrict__ x4,
    const float* __restrict__ p1, const float* __restrict__ p2,
    const float* __restrict__ We2_l, const float* __restrict__ wd2_l,
    const float* __restrict__ be1_l, const float* __restrict__ be2_l,
    float* __restrict__ m_ws, float4* __restrict__ rc_ws, int E)
{
  extern __shared__ float lds[];
  float* ldsW = lds;
  float* ldsU = lds + 16384;
  int tid = threadIdx.x;
  stage_w128(We2_l, ldsW, tid);
  __syncthreads();
  const int wave = tid >> 6, lane = tid & 63;
  float* myU = ldsU + wave*1024;
  const int sw = (lane & 7) << 2;
  const float wd2a = wd2_l[lane], wd2b = wd2_l[lane+64];
  const float be1a = be1_l[lane], be1b = be1_l[lane+64];
  const float be2a = be2_l[lane], be2b = be2_l[lane+64];
  const int gw = blockIdx.x*16 + wave;
  const int nw = gridDim.x*16;
  const int ntiles = E >> 3;
  for (int tt = gw; tt < ntiles; tt += nw) {
    int eb = tt << 3;
    #pragma unroll
    for (int e = 0; e < 8; ++e) {
      int r = rowp[eb+e], c = colp[eb+e];
      float4 xr = x4[r], xc = x4[c];
      float dx = xr.x-xc.x, dy = xr.y-xc.y, dz = xr.z-xc.z;
      float d2 = dx*dx + dy*dy + dz*dz;
      if (lane == e) rc_ws[eb+e] = make_float4(dx, dy, dz, 0.f);
      float ua = silu_f(p1[(size_t)r*HID+lane]    + p2[(size_t)c*HID+lane]    + d2*wd2a + be1a);
      float ub = silu_f(p1[(size_t)r*HID+lane+64] + p2[(size_t)c*HID+lane+64] + d2*wd2b + be1b);
      myU[e*128 + lane]      = ua;
      myU[e*128 + lane + 64] = ub;
    }
    float ma[8], mb[8];
    #pragma unroll
    for (int e = 0; e < 8; ++e) { ma[e] = 0.f; mb[e] = 0.f; }
    #pragma unroll 8
    for (int k0 = 0; k0 < 128; k0 += 4) {
      int kk = k0 ^ sw;
      float4 wA = *(const float4*)&ldsW[lane*128 + kk];
      float4 wB = *(const float4*)&ldsW[(lane+64)*128 + kk];
      #pragma unroll
      for (int e = 0; e < 8; ++e) {
        float4 u = *(const float4*)&myU[e*128 + k0];
        dot4(ma[e], u, wA); dot4(mb[e], u, wB);
      }
    }
    #pragma unroll
    for (int e = 0; e < 8; ++e) {
      m_ws[(size_t)(eb+e)*HID + lane]      = silu_f(ma[e] + be2a);
      m_ws[(size_t)(eb+e)*HID + lane + 64] = silu_f(mb[e] + be2b);
    }
  }
}

// ---------------- edge2: coef = silu(m@Wc1+bc1)@Wc2; rc = rel*coef ----------------
__global__ __launch_bounds__(1024, 4) void edge2_kernel(
    const float* __restrict__ Wc1_l, const float* __restrict__ bc1_l,
    const float* __restrict__ Wc2_l,
    const float* __restrict__ m_ws, float4* __restrict__ rc_ws, int E)
{
  extern __shared__ float lds[];
  float* ldsW = lds;
  float* ldsU = lds + 16384;
  int tid = threadIdx.x;
  stage_w128(Wc1_l, ldsW, tid);
  __syncthreads();
  const int wave = tid >> 6, lane = tid & 63;
  float* myU = ldsU + wave*1024;
  const int sw = (lane & 7) << 2;
  const float bc1a = bc1_l[lane], bc1b = bc1_l[lane+64];
  const float wc2a = Wc2_l[lane], wc2b = Wc2_l[lane+64];
  const int gw = blockIdx.x*16 + wave;
  const int nw = gridDim.x*16;
  const int ntiles = E >> 3;
  for (int tt = gw; tt < ntiles; tt += nw) {
    int eb = tt << 3;
    #pragma unroll
    for (int e = 0; e < 8; ++e) {
      myU[e*128 + lane]      = m_ws[(size_t)(eb+e)*HID + lane];
      myU[e*128 + lane + 64] = m_ws[(size_t)(eb+e)*HID + lane + 64];
    }
    float ta[8], tb[8];
    #pragma unroll
    for (int e = 0; e < 8; ++e) { ta[e] = 0.f; tb[e] = 0.f; }
    #pragma unroll 8
    for (int k0 = 0; k0 < 128; k0 += 4) {
      int kk = k0 ^ sw;
      float4 wA = *(const float4*)&ldsW[lane*128 + kk];
      float4 wB = *(const float4*)&ldsW[(lane+64)*128 + kk];
      #pragma unroll
      for (int e = 0; e < 8; ++e) {
        float4 u = *(const float4*)&myU[e*128 + k0];
        dot4(ta[e], u, wA); dot4(tb[e], u, wB);
      }
    }
    #pragma unroll
    for (int e = 0; e < 8; ++e) {
      float pa = silu_f(ta[e] + bc1a);
      float pb = silu_f(tb[e] + bc1b);
      float pt = pa*wc2a + pb*wc2b;
      #pragma unroll
      for (int o = 32; o > 0; o >>= 1) pt += __shfl_down(pt, o);
      if (lane == 0) {
        float4 rel = rc_ws[eb+e];
        rc_ws[eb+e] = make_float4(rel.x*pt, rel.y*pt, rel.z*pt, 0.f);
      }
    }
  }
}

// ---------------- aggregation: agg[v] = sum m, x[v] += sum rel*coef ----------------
__global__ void agg_kernel(const int* __restrict__ offp, const int* __restrict__ perm,
                           const float* __restrict__ m_ws, const float4* __restrict__ rc_ws,
                           float* __restrict__ agg, float4* __restrict__ x4, int V)
{
  int wave = threadIdx.x >> 6, lane = threadIdx.x & 63;
  int v = blockIdx.x*4 + wave;
  if (v >= V) return;
  int s = offp[v], e = offp[v+1];
  float acc0 = 0.f, acc1 = 0.f;
  float rx = 0.f, ry = 0.f, rz = 0.f;
  for (int i = s; i < e; ++i) {
    int ed = perm[i];
    float2 mv = ((const float2*)m_ws)[(size_t)ed*64 + lane];
    acc0 += mv.x; acc1 += mv.y;
    float4 rc = rc_ws[ed];
    rx += rc.x; ry += rc.y; rz += rc.z;
  }
  ((float2*)agg)[(size_t)v*64 + lane] = make_float2(acc0, acc1);
  if (lane == 0) {
    float4 xv = x4[v];
    xv.x += rx; xv.y += ry; xv.z += rz;
    x4[v] = xv;
  }
}

// ---------------- nu1a: tmp = h@Wn1_top + bn1 ----------------
__global__ __launch_bounds__(1024, 4) void nu1a_kernel(
    const float* __restrict__ h, const float* __restrict__ Wtop,
    const float* __restrict__ bn1_l, float* __restrict__ tmp, int V)
{
  extern __shared__ float lds[];
  float* ldsW = lds;
  float* ldsU = lds + 16384;
  int tid = threadIdx.x;
  stage_w128(Wtop, ldsW, tid);
  __syncthreads();
  const int wave = tid >> 6, lane = tid & 63;
  float* myU = ldsU + wave*1024;
  const int sw = (lane & 7) << 2;
  const float b_a = bn1_l[lane], b_b = bn1_l[lane+64];
  const int gw = blockIdx.x*16 + wave;
  const int nw = gridDim.x*16;
  const int ntiles = V >> 3;
  for (int tt = gw; tt < ntiles; tt += nw) {
    int vb = tt << 3;
    #pragma unroll
    for (int n = 0; n < 8; ++n) {
      myU[n*128 + lane]      = h[(size_t)(vb+n)*HID + lane];
      myU[n*128 + lane + 64] = h[(size_t)(vb+n)*HID + lane + 64];
    }
    float aa[8], ab[8];
    #pragma unroll
    for (int n = 0; n < 8; ++n) { aa[n] = 0.f; ab[n] = 0.f; }
    #pragma unroll 8
    for (int k0 = 0; k0 < 128; k0 += 4) {
      int kk = k0 ^ sw;
      float4 wA = *(const float4*)&ldsW[lane*128 + kk];
      float4 wB = *(const float4*)&ldsW[(lane+64)*128 + kk];
      #pragma unroll
      for (int n = 0; n < 8; ++n) {
        float4 u = *(const float4*)&myU[n*128 + k0];
        dot4(aa[n], u, wA); dot4(ab[n], u, wB);
      }
    }
    #pragma unroll
    for (int n = 0; n < 8; ++n) {
      tmp[(size_t)(vb+n)*HID + lane]      = aa[n] + b_a;
      tmp[(size_t)(vb+n)*HID + lane + 64] = ab[n] + b_b;
    }
  }
}

// ---------------- nu1b: q = silu(tmp + agg@Wn1_bot) ----------------
__global__ __launch_bounds__(1024, 4) void nu1b_kernel(
    const float* __restrict__ tmp, const float* __restrict__ agg,
    const float* __restrict__ Wbot, float* __restrict__ q, int V)
{
  extern __shared__ float lds[];
  float* ldsW = lds;
  float* ldsU = lds + 16384;
  int tid = threadIdx.x;
  stage_w128(Wbot, ldsW, tid);
  __syncthreads();
  const int wave = tid >> 6, lane = tid & 63;
  float* myU = ldsU + wave*1024;
  const int sw = (lane & 7) << 2;
  const int gw = blockIdx.x*16 + wave;
  const int nw = gridDim.x*16;
  const int ntiles = V >> 3;
  for (int tt = gw; tt < ntiles; tt += nw) {
    int vb = tt << 3;
    #pragma unroll
    for (int n = 0; n < 8; ++n) {
      myU[n*128 + lane]      = agg[(size_t)(vb+n)*HID + lane];
      myU[n*128 + lane + 64] = agg[(size_t)(vb+n)*HID + lane + 64];
    }
    float aa[8], ab[8];
    #pragma unroll
    for (int n = 0; n < 8; ++n) { aa[n] = 0.f; ab[n] = 0.f; }
    #pragma unroll 8
    for (int k0 = 0; k0 < 128; k0 += 4) {
      int kk = k0 ^ sw;
      float4 wA = *(const float4*)&ldsW[lane*128 + kk];
      float4 wB = *(const float4*)&ldsW[(lane+64)*128 + kk];
      #pragma unroll
      for (int n = 0; n < 8; ++n) {
        float4 u = *(const float4*)&myU[n*128 + k0];
        dot4(aa[n], u, wA); dot4(ab[n], u, wB);
      }
    }
    #pragma unroll
    for (int n = 0; n < 8; ++n) {
      q[(size_t)(vb+n)*HID + lane]      = silu_f(aa[n] + tmp[(size_t)(vb+n)*HID + lane]);
      q[(size_t)(vb+n)*HID + lane + 64] = silu_f(ab[n] + tmp[(size_t)(vb+n)*HID + lane + 64]);
    }
  }
}

// ---------------- nu2: h += q@Wn2 + bn2 ----------------
__global__ __launch_bounds__(1024, 4) void nu2_kernel(
    const float* __restrict__ q, const float* __restrict__ Wn2_l,
    const float* __restrict__ bn2_l, float* __restrict__ h, int V)
{
  extern __shared__ float lds[];
  float* ldsW = lds;
  float* ldsU = lds + 16384;
  int tid = threadIdx.x;
  stage_w128(Wn2_l, ldsW, tid);
  __syncthreads();
  const int wave = tid >> 6, lane = tid & 63;
  float* myU = ldsU + wave*1024;
  const int sw = (lane & 7) << 2;
  const float b_a = bn2_l[lane], b_b = bn2_l[lane+64];
  const int gw = blockIdx.x*16 + wave;
  const int nw = gridDim.x*16;
  const int ntiles = V >> 3;
  for (int tt = gw; tt < ntiles; tt += nw) {
    int vb = tt << 3;
    #pragma unroll
    for (int n = 0; n < 8; ++n) {
      myU[n*128 + lane]      = q[(size_t)(vb+n)*HID + lane];
      myU[n*128 + lane + 64] = q[(size_t)(vb+n)*HID + lane + 64];
    }
    float aa[8], ab[8];
    #pragma unroll
    for (int n = 0; n < 8; ++n) { aa[n] = 0.f; ab[n] = 0.f; }
    #pragma unroll 8
    for (int k0 = 0; k0 < 128; k0 += 4) {
      int kk = k0 ^ sw;
      float4 wA = *(const float4*)&ldsW[lane*128 + kk];
      float4 wB = *(const float4*)&ldsW[(lane+64)*128 + kk];
      #pragma unroll
      for (int n = 0; n < 8; ++n) {
        float4 u = *(const float4*)&myU[n*128 + k0];
        dot4(aa[n], u, wA); dot4(ab[n], u, wB);
      }
    }
    #pragma unroll
    for (int n = 0; n < 8; ++n) {
      h[(size_t)(vb+n)*HID + lane]      += aa[n] + b_a;
      h[(size_t)(vb+n)*HID + lane + 64] += ab[n] + b_b;
    }
  }
}

__global__ void vel_kernel(const float4* __restrict__ x4, const float* __restrict__ pos,
                           float* __restrict__ out, int V) {
  int v = blockIdx.x * blockDim.x + threadIdx.x;
  if (v < V) {
    float4 xv = x4[v];
    out[3*v]   = xv.x - pos[3*v];
    out[3*v+1] = xv.y - pos[3*v+1];
    out[3*v+2] = xv.z - pos[3*v+2];
  }
}

extern "C" void kernel_launch(void* const* d_in, const int* in_sizes, int n_in,
                              void* d_out, int out_size, void* d_ws, size_t ws_size,
                              hipStream_t stream) {
  const float* pos   = (const float*)d_in[0];
  const float* t     = (const float*)d_in[1];
  const float* z     = (const float*)d_in[2];
  const int*   ei    = (const int*)d_in[3];
  const int*   batch = (const int*)d_in[4];
  const float* te_w1 = (const float*)d_in[5];
  const float* te_b1 = (const float*)d_in[6];
  const float* te_w2 = (const float*)d_in[7];
  const float* te_b2 = (const float*)d_in[8];
  const float* cp_w  = (const float*)d_in[9];
  const float* cp_b  = (const float*)d_in[10];
  const float* We1   = (const float*)d_in[11];
  const float* be1   = (const float*)d_in[12];
  const float* We2   = (const float*)d_in[13];
  const float* be2   = (const float*)d_in[14];
  const float* Wc1   = (const float*)d_in[15];
  const float* bc1   = (const float*)d_in[16];
  const float* Wc2   = (const float*)d_in[17];
  const float* Wn1   = (const float*)d_in[18];
  const float* bn1   = (const float*)d_in[19];
  const float* Wn2   = (const float*)d_in[20];
  const float* bn2   = (const float*)d_in[21];

  const int V = in_sizes[4];
  const int E = in_sizes[3] / 2;
  const int* rowp = ei;
  const int* colp = ei + E;

  char* base = (char*)d_ws;
  size_t off_b = 0;
  auto alloc = [&](size_t bytes) -> char* {
    char* p = base + off_b;
    off_b += (bytes + 255) & ~(size_t)255;
    return p;
  };
  float*  h     = (float*) alloc((size_t)V*HID*4);
  float*  pA    = (float*) alloc((size_t)V*HID*4);   // p1, later nu1a tmp
  float*  pB    = (float*) alloc((size_t)V*HID*4);   // p2, later agg
  float4* x4    = (float4*)alloc((size_t)V*16);
  float*  m_ws  = (float*) alloc((size_t)E*HID*4);   // m, later q
  float4* rc_ws = (float4*)alloc((size_t)E*16);      // rel, then rel*coef
  float*  hb    = (float*) alloc(8*HID*4);
  int*    cnt   = (int*)   alloc((size_t)V*4);
  int*    offp  = (int*)   alloc((size_t)(V+1)*4);
  int*    fill  = (int*)   alloc((size_t)V*4);
  int*    perm  = (int*)   alloc((size_t)E*4);
  (void)ws_size; (void)n_in; (void)out_size;

  const int DLDS = 131072;
  hipFuncSetAttribute((const void*)phalf_kernel, hipFuncAttributeMaxDynamicSharedMemorySize, DLDS);
  hipFuncSetAttribute((const void*)edge1_kernel, hipFuncAttributeMaxDynamicSharedMemorySize, DLDS);
  hipFuncSetAttribute((const void*)edge2_kernel, hipFuncAttributeMaxDynamicSharedMemorySize, DLDS);
  hipFuncSetAttribute((const void*)nu1a_kernel,  hipFuncAttributeMaxDynamicSharedMemorySize, DLDS);
  hipFuncSetAttribute((const void*)nu1b_kernel,  hipFuncAttributeMaxDynamicSharedMemorySize, DLDS);
  hipFuncSetAttribute((const void*)nu2_kernel,   hipFuncAttributeMaxDynamicSharedMemorySize, DLDS);

  hb_kernel<<<8, 128, 0, stream>>>(t, z, te_w1, te_b1, te_w2, te_b2, cp_w, cp_b, hb);
  scatter_h_kernel<<<(V*32 + 255)/256, 256, 0, stream>>>(batch, hb, h, V);
  packx_kernel<<<(V + 255)/256, 256, 0, stream>>>(pos, x4, V);
  hipMemsetAsync(cnt, 0, (size_t)V*4, stream);
  hipMemsetAsync(fill, 0, (size_t)V*4, stream);
  hist_kernel<<<(E + 255)/256, 256, 0, stream>>>(rowp, cnt, E);
  scan_kernel<<<1, 1024, 0, stream>>>(cnt, offp, V);
  scatter_perm_kernel<<<(E + 255)/256, 256, 0, stream>>>(rowp, offp, fill, perm, E);

  for (int l = 0; l < NLAY; ++l) {
    const float* We1_l = We1 + (size_t)l*257*HID;
    const float* wd2_l = We1_l + 256*HID;        // We1[l][256][:]
    const float* We2_l = We2 + (size_t)l*HID*HID;
    const float* Wc1_l = Wc1 + (size_t)l*HID*HID;
    const float* Wc2_l = Wc2 + (size_t)l*HID;
    const float* Wn1_l = Wn1 + (size_t)l*256*HID;
    const float* Wn2_l = Wn2 + (size_t)l*HID*HID;
    const float* be1_l = be1 + l*HID;
    const float* be2_l = be2 + l*HID;
    const float* bc1_l = bc1 + l*HID;
    const float* bn1_l = bn1 + l*HID;
    const float* bn2_l = bn2 + l*HID;

    phalf_kernel<<<256, 1024, DLDS, stream>>>(h, We1_l, pA, V);                 // p1
    phalf_kernel<<<256, 1024, DLDS, stream>>>(h, We1_l + 128*HID, pB, V);       // p2
    edge1_kernel<<<256, 1024, DLDS, stream>>>(rowp, colp, x4, pA, pB, We2_l,
                                              wd2_l, be1_l, be2_l, m_ws, rc_ws, E);
    edge2_kernel<<<256, 1024, DLDS, stream>>>(Wc1_l, bc1_l, Wc2_l, m_ws, rc_ws, E);
    agg_kernel<<<(V + 3)/4, 256, 0, stream>>>(offp, perm, m_ws, rc_ws, pB, x4, V);
    nu1a_kernel<<<256, 1024, DLDS, stream>>>(h, Wn1_l, bn1_l, pA, V);
    nu1b_kernel<<<256, 1024, DLDS, stream>>>(pA, pB, Wn1_l + 128*HID, m_ws, V);
    nu2_kernel<<<256, 1024, DLDS, stream>>>(m_ws, Wn2_l, bn2_l, h, V);
  }
  vel_kernel<<<(V + 255)/256, 256, 0, stream>>>(x4, pos, (float*)d_out, V);
}

// Round 4
// 2309.741 us; speedup vs baseline: 1.1793x; 1.1055x over previous
//
#include <hip/hip_runtime.h>

#define HID 128
#define NLAY 4

typedef float f32x4 __attribute__((ext_vector_type(4)));
typedef short bf16x8 __attribute__((ext_vector_type(8)));

union FragU { uint4 u; bf16x8 v; };

__device__ __forceinline__ float silu_f(float x) {
  return x / (1.0f + __expf(-x));
}

__device__ __forceinline__ void dot4(float& acc, const float4& u, const float4& wv) {
  acc = fmaf(u.x, wv.x, fmaf(u.y, wv.y, fmaf(u.z, wv.z, fmaf(u.w, wv.w, acc))));
}

// pack fp32 -> (hi bf16 in low16, lo bf16 in high16)
__device__ __forceinline__ unsigned int pack_pair(float x) {
  unsigned int bx = __float_as_uint(x);
  unsigned int hi = bx & 0xffff0000u;
  float lof = x - __uint_as_float(hi);
  return (bx >> 16) | (__float_as_uint(lof) & 0xffff0000u);
}

__device__ __forceinline__ float unpack_sum(unsigned int p) {
  return __uint_as_float(p << 16) + __uint_as_float(p & 0xffff0000u);
}

// build A_hi/A_lo fragments (8 elts) from 8 packed pairs
__device__ __forceinline__ void unpack_frags(const uint4& a, const uint4& b,
                                             FragU& hi, FragU& lo) {
  hi.u.x = __builtin_amdgcn_perm(a.y, a.x, 0x05040100u);
  hi.u.y = __builtin_amdgcn_perm(a.w, a.z, 0x05040100u);
  hi.u.z = __builtin_amdgcn_perm(b.y, b.x, 0x05040100u);
  hi.u.w = __builtin_amdgcn_perm(b.w, b.z, 0x05040100u);
  lo.u.x = __builtin_amdgcn_perm(a.y, a.x, 0x07060302u);
  lo.u.y = __builtin_amdgcn_perm(a.w, a.z, 0x07060302u);
  lo.u.z = __builtin_amdgcn_perm(b.y, b.x, 0x07060302u);
  lo.u.w = __builtin_amdgcn_perm(b.w, b.z, 0x07060302u);
}

// ---------------- weight prep: [128k][128o] fp32 -> MFMA B-frag streams (hi, lo) ----
// out[id] (hi) / out[16384+id] (lo), id = ((kb*8+ob)*64 + lane)*8 + i
__global__ void wprep_kernel(const float* __restrict__ W, unsigned short* __restrict__ out) {
  int id = blockIdx.x * 256 + threadIdx.x;
  if (id >= 16384) return;
  int i = id & 7;
  int lane = (id >> 3) & 63;
  int obkb = id >> 9;                 // kb*8+ob
  int k = (obkb >> 3) * 32 + ((lane >> 4) << 3) + i;
  int col = (obkb & 7) * 16 + (lane & 15);
  float x = W[k * 128 + col];
  unsigned int bx = __float_as_uint(x);
  unsigned int hi = bx & 0xffff0000u;
  float lof = x - __uint_as_float(hi);
  out[id] = (unsigned short)(bx >> 16);
  out[16384 + id] = (unsigned short)(__float_as_uint(lof) >> 16);
}

// ---------------- conditioning: h table (B=8 x 128) ----------------
__global__ void hb_kernel(const float* __restrict__ t, const float* __restrict__ z,
                          const float* __restrict__ te_w1, const float* __restrict__ te_b1,
                          const float* __restrict__ te_w2, const float* __restrict__ te_b2,
                          const float* __restrict__ cp_w, const float* __restrict__ cp_b,
                          float* __restrict__ hb) {
  int b = blockIdx.x;
  int j = threadIdx.x;
  float tv = t[b];
  float e1[16];
  #pragma unroll
  for (int i = 0; i < 16; ++i) e1[i] = silu_f(tv * te_w1[i] + te_b1[i]);
  float acc = cp_b[j];
  for (int i = 0; i < 64; ++i) acc += z[b*64 + i] * cp_w[i*HID + j];
  #pragma unroll
  for (int i = 0; i < 16; ++i) {
    float te = te_b2[i];
    #pragma unroll
    for (int k = 0; k < 16; ++k) te += e1[k] * te_w2[k*16 + i];
    acc += te * cp_w[(64 + i)*HID + j];
  }
  hb[b*HID + j] = acc;
}

__global__ void scatter_h_kernel(const int* __restrict__ batch, const float* __restrict__ hb,
                                 float* __restrict__ h, int V) {
  int idx = blockIdx.x * blockDim.x + threadIdx.x;
  if (idx < V * 32) {
    int v = idx >> 5, c = idx & 31;
    int b = batch[v];
    ((float4*)h)[(size_t)v*32 + c] = ((const float4*)hb)[b*32 + c];
  }
}

__global__ void packx_kernel(const float* __restrict__ pos, float4* __restrict__ x4, int V) {
  int v = blockIdx.x * blockDim.x + threadIdx.x;
  if (v < V) x4[v] = make_float4(pos[3*v], pos[3*v+1], pos[3*v+2], 0.f);
}

// ---------------- CSR build ----------------
__global__ void hist_kernel(const int* __restrict__ rowp, int* __restrict__ cnt, int E) {
  int e = blockIdx.x * blockDim.x + threadIdx.x;
  if (e < E) atomicAdd(&cnt[rowp[e]], 1);
}

__global__ void scan_kernel(const int* __restrict__ cnt, int* __restrict__ offp, int V) {
  __shared__ int s[1024];
  __shared__ int carry_s;
  int tid = threadIdx.x;
  if (tid == 0) carry_s = 0;
  __syncthreads();
  for (int base = 0; base < V; base += 1024) {
    int v = base + tid;
    int val = (v < V) ? cnt[v] : 0;
    s[tid] = val;
    __syncthreads();
    for (int d = 1; d < 1024; d <<= 1) {
      int tval = (tid >= d) ? s[tid - d] : 0;
      __syncthreads();
      s[tid] += tval;
      __syncthreads();
    }
    int c0 = carry_s;
    if (v < V) offp[v] = c0 + s[tid] - val;
    int tot = s[1023];
    __syncthreads();
    if (tid == 0) carry_s = c0 + tot;
    __syncthreads();
  }
  if (tid == 0) offp[V] = carry_s;
}

__global__ void scatter_perm_kernel(const int* __restrict__ rowp, const int* __restrict__ offp,
                                    int* __restrict__ fill, int* __restrict__ perm, int E) {
  int e = blockIdx.x * blockDim.x + threadIdx.x;
  if (e < E) {
    int r = rowp[e];
    int p = offp[r] + atomicAdd(&fill[r], 1);
    perm[p] = e;
  }
}

// ---------------- phalf (VALU path, unchanged) ----------------
__device__ __forceinline__ void stage_w128(const float* __restrict__ W, float* ldsW, int tid) {
  for (int i4 = tid; i4 < 4096; i4 += 1024) {
    float4 wv = ((const float4*)W)[i4];
    int flat = i4 << 2;
    int k = flat >> 7;
    int c = flat & 127;
    const float* pv = (const float*)&wv;
    #pragma unroll
    for (int q = 0; q < 4; ++q) {
      int o = c + q;
      ldsW[o*128 + (k ^ ((o & 7) << 2))] = pv[q];
    }
  }
}

__global__ __launch_bounds__(1024, 4) void phalf_kernel(
    const float* __restrict__ h, const float* __restrict__ W128,
    float* __restrict__ pout, int V)
{
  extern __shared__ float lds[];
  float* ldsW = lds;
  float* ldsU = lds + 16384;
  int tid = threadIdx.x;
  stage_w128(W128, ldsW, tid);
  __syncthreads();
  const int wave = tid >> 6, lane = tid & 63;
  float* myU = ldsU + wave*1024;
  const int sw = (lane & 7) << 2;
  const int gw = blockIdx.x*16 + wave;
  const int nw = gridDim.x*16;
  const int ntiles = V >> 3;
  for (int tt = gw; tt < ntiles; tt += nw) {
    int vb = tt << 3;
    #pragma unroll
    for (int n = 0; n < 8; ++n) {
      myU[n*128 + lane]      = h[(size_t)(vb+n)*HID + lane];
      myU[n*128 + lane + 64] = h[(size_t)(vb+n)*HID + lane + 64];
    }
    float aa[8], ab[8];
    #pragma unroll
    for (int n = 0; n < 8; ++n) { aa[n] = 0.f; ab[n] = 0.f; }
    #pragma unroll 8
    for (int k0 = 0; k0 < 128; k0 += 4) {
      int kk = k0 ^ sw;
      float4 wA = *(const float4*)&ldsW[lane*128 + kk];
      float4 wB = *(const float4*)&ldsW[(lane+64)*128 + kk];
      #pragma unroll
      for (int n = 0; n < 8; ++n) {
        float4 u = *(const float4*)&myU[n*128 + k0];
        dot4(aa[n], u, wA); dot4(ab[n], u, wB);
      }
    }
    #pragma unroll
    for (int n = 0; n < 8; ++n) {
      pout[(size_t)(vb+n)*HID + lane]      = aa[n];
      pout[(size_t)(vb+n)*HID + lane + 64] = ab[n];
    }
  }
}

// ---------------- edge1 (MFMA): u = silu(p1[r]+p2[c]+d2*wd2+be1); m = silu(u@We2+be2) ----
// B-frags (We2 hi/lo) in LDS (64KB) + per-wave u pair-tile (16KB x 4 waves) = 128KB.
__global__ __launch_bounds__(256, 1) void edge1_kernel(
    const int* __restrict__ rowp, const int* __restrict__ colp,
    const float4* __restrict__ x4,
    const float* __restrict__ p1, const float* __restrict__ p2,
    const unsigned short* __restrict__ wfr,
    const float* __restrict__ wd2_l, const float* __restrict__ be1_l,
    const float* __restrict__ be2_l,
    unsigned int* __restrict__ m_pairs, float4* __restrict__ rc_ws, int E)
{
  extern __shared__ char smem[];
  uint4* ldsB = (uint4*)smem;          // hi: [0..2047], lo: [2048..4095]
  int tid = threadIdx.x;
  for (int i = tid; i < 4096; i += 256) ldsB[i] = ((const uint4*)wfr)[i];
  __syncthreads();
  const int wave = tid >> 6, lane = tid & 63;
  const int g = lane >> 4, c16 = lane & 15;
  char* uB = smem + 65536 + wave * 16384;   // 32 rows x 512 B (pair-packed, XOR-swizzled)
  float2 wd2v = ((const float2*)wd2_l)[lane];
  float2 be1v = ((const float2*)be1_l)[lane];
  float be2_r[8];
  #pragma unroll
  for (int ob = 0; ob < 8; ++ob) be2_r[ob] = be2_l[ob*16 + c16];
  const int gw = blockIdx.x*4 + wave;
  const int nw = gridDim.x*4;
  const int ntiles = E >> 5;
  for (int tt = gw; tt < ntiles; tt += nw) {
    int eb = tt << 5;
    int r_l = 0, c_l = 0; float d2_l = 0.f;
    if (lane < 32) {
      r_l = rowp[eb + lane]; c_l = colp[eb + lane];
      float4 xr = x4[r_l], xc = x4[c_l];
      float dx = xr.x-xc.x, dy = xr.y-xc.y, dz = xr.z-xc.z;
      d2_l = dx*dx + dy*dy + dz*dz;
      rc_ws[eb + lane] = make_float4(dx, dy, dz, 0.f);
    }
    #pragma unroll
    for (int e = 0; e < 32; ++e) {
      int re = __shfl(r_l, e), ce = __shfl(c_l, e);
      float d2e = __shfl(d2_l, e);
      float2 a = ((const float2*)p1)[re*64 + lane];
      float2 b = ((const float2*)p2)[ce*64 + lane];
      float u0 = silu_f(a.x + b.x + d2e*wd2v.x + be1v.x);
      float u1 = silu_f(a.y + b.y + d2e*wd2v.y + be1v.y);
      int row = e & 15, s = e >> 4;
      int off = (((lane << 3) & 0x1F0) ^ ((row & 7) << 4)) + ((lane << 3) & 8);
      *(uint2*)(uB + (s*16 + row)*512 + off) = make_uint2(pack_pair(u0), pack_pair(u1));
    }
    f32x4 zero4 = {0.f, 0.f, 0.f, 0.f};
    f32x4 acc[2][8];
    #pragma unroll
    for (int s = 0; s < 2; ++s)
      #pragma unroll
      for (int ob = 0; ob < 8; ++ob) acc[s][ob] = zero4;
    #pragma unroll
    for (int kb = 0; kb < 4; ++kb) {
      FragU Ah[2], Al[2];
      #pragma unroll
      for (int s = 0; s < 2; ++s) {
        int kbyte = kb*128 + g*32;
        int swz = (c16 & 7) << 4;
        const char* base = uB + (s*16 + c16)*512;
        uint4 a = *(const uint4*)(base + (kbyte ^ swz));
        uint4 b = *(const uint4*)(base + ((kbyte + 16) ^ swz));
        unpack_frags(a, b, Ah[s], Al[s]);
      }
      #pragma unroll
      for (int ob = 0; ob < 8; ++ob) {
        FragU Bh, Bl;
        Bh.u = ldsB[(kb*8 + ob)*64 + lane];
        Bl.u = ldsB[2048 + (kb*8 + ob)*64 + lane];
        #pragma unroll
        for (int s = 0; s < 2; ++s) {
          acc[s][ob] = __builtin_amdgcn_mfma_f32_16x16x32_bf16(Al[s].v, Bh.v, acc[s][ob], 0, 0, 0);
          acc[s][ob] = __builtin_amdgcn_mfma_f32_16x16x32_bf16(Ah[s].v, Bl.v, acc[s][ob], 0, 0, 0);
          acc[s][ob] = __builtin_amdgcn_mfma_f32_16x16x32_bf16(Ah[s].v, Bh.v, acc[s][ob], 0, 0, 0);
        }
      }
    }
    #pragma unroll
    for (int s = 0; s < 2; ++s)
      #pragma unroll
      for (int ob = 0; ob < 8; ++ob)
        #pragma unroll
        for (int r = 0; r < 4; ++r) {
          int e = eb + s*16 + 4*g + r;
          float mval = silu_f(acc[s][ob][r] + be2_r[ob]);
          m_pairs[(size_t)e*128 + ob*16 + c16] = pack_pair(mval);
        }
  }
}

// ---------------- edge2 (MFMA): coef = silu(m@Wc1+bc1)@Wc2; rc_ws = rel*coef ----------
__global__ __launch_bounds__(512, 2) void edge2_kernel(
    const unsigned short* __restrict__ wfr,
    const float* __restrict__ bc1_l, const float* __restrict__ Wc2_l,
    const unsigned int* __restrict__ m_pairs, float4* __restrict__ rc_ws, int E)
{
  extern __shared__ char smem[];
  uint4* ldsB = (uint4*)smem;
  int tid = threadIdx.x;
  for (int i = tid; i < 4096; i += 512) ldsB[i] = ((const uint4*)wfr)[i];
  __syncthreads();
  const int wave = tid >> 6, lane = tid & 63;
  const int g = lane >> 4, c16 = lane & 15;
  float bc1_r[8], wc2_r[8];
  #pragma unroll
  for (int ob = 0; ob < 8; ++ob) {
    bc1_r[ob] = bc1_l[ob*16 + c16];
    wc2_r[ob] = Wc2_l[ob*16 + c16];
  }
  const int gw = blockIdx.x*8 + wave;
  const int nw = gridDim.x*8;
  const int ntiles = E >> 5;
  for (int tt = gw; tt < ntiles; tt += nw) {
    int eb = tt << 5;
    f32x4 zero4 = {0.f, 0.f, 0.f, 0.f};
    f32x4 acc[2][8];
    #pragma unroll
    for (int s = 0; s < 2; ++s)
      #pragma unroll
      for (int ob = 0; ob < 8; ++ob) acc[s][ob] = zero4;
    #pragma unroll
    for (int kb = 0; kb < 4; ++kb) {
      FragU Ah[2], Al[2];
      #pragma unroll
      for (int s = 0; s < 2; ++s) {
        const unsigned int* rp = m_pairs + (size_t)(eb + s*16 + c16)*128 + kb*32 + g*8;
        uint4 a = *(const uint4*)rp;
        uint4 b = *(const uint4*)(rp + 4);
        unpack_frags(a, b, Ah[s], Al[s]);
      }
      #pragma unroll
      for (int ob = 0; ob < 8; ++ob) {
        FragU Bh, Bl;
        Bh.u = ldsB[(kb*8 + ob)*64 + lane];
        Bl.u = ldsB[2048 + (kb*8 + ob)*64 + lane];
        #pragma unroll
        for (int s = 0; s < 2; ++s) {
          acc[s][ob] = __builtin_amdgcn_mfma_f32_16x16x32_bf16(Al[s].v, Bh.v, acc[s][ob], 0, 0, 0);
          acc[s][ob] = __builtin_amdgcn_mfma_f32_16x16x32_bf16(Ah[s].v, Bl.v, acc[s][ob], 0, 0, 0);
          acc[s][ob] = __builtin_amdgcn_mfma_f32_16x16x32_bf16(Ah[s].v, Bh.v, acc[s][ob], 0, 0, 0);
        }
      }
    }
    float part[2][4];
    #pragma unroll
    for (int s = 0; s < 2; ++s)
      #pragma unroll
      for (int r = 0; r < 4; ++r) part[s][r] = 0.f;
    #pragma unroll
    for (int s = 0; s < 2; ++s)
      #pragma unroll
      for (int ob = 0; ob < 8; ++ob)
        #pragma unroll
        for (int r = 0; r < 4; ++r) {
          float tv = silu_f(acc[s][ob][r] + bc1_r[ob]);
          part[s][r] += tv * wc2_r[ob];
        }
    #pragma unroll
    for (int s = 0; s < 2; ++s)
      #pragma unroll
      for (int r = 0; r < 4; ++r) {
        #pragma unroll
        for (int m = 1; m < 16; m <<= 1) part[s][r] += __shfl_xor(part[s][r], m);
      }
    if (c16 == 0) {
      #pragma unroll
      for (int s = 0; s < 2; ++s)
        #pragma unroll
        for (int r = 0; r < 4; ++r) {
          int e = eb + s*16 + 4*g + r;
          float4 rel = rc_ws[e];
          float cf = part[s][r];
          rc_ws[e] = make_float4(rel.x*cf, rel.y*cf, rel.z*cf, 0.f);
        }
    }
  }
}

// ---------------- aggregation (m from pairs) ----------------
__global__ void agg_kernel(const int* __restrict__ offp, const int* __restrict__ perm,
                           const unsigned int* __restrict__ m_pairs,
                           const float4* __restrict__ rc_ws,
                           float* __restrict__ agg, float4* __restrict__ x4, int V)
{
  int wave = threadIdx.x >> 6, lane = threadIdx.x & 63;
  int v = blockIdx.x*4 + wave;
  if (v >= V) return;
  int s = offp[v], e = offp[v+1];
  float acc0 = 0.f, acc1 = 0.f;
  float rx = 0.f, ry = 0.f, rz = 0.f;
  for (int i = s; i < e; ++i) {
    int ed = perm[i];
    uint2 mv = ((const uint2*)m_pairs)[(size_t)ed*64 + lane];
    acc0 += unpack_sum(mv.x);
    acc1 += unpack_sum(mv.y);
    float4 rc = rc_ws[ed];
    rx += rc.x; ry += rc.y; rz += rc.z;
  }
  ((float2*)agg)[(size_t)v*64 + lane] = make_float2(acc0, acc1);
  if (lane == 0) {
    float4 xv = x4[v];
    xv.x += rx; xv.y += ry; xv.z += rz;
    x4[v] = xv;
  }
}

// ---------------- node updates (VALU path, unchanged) ----------------
__global__ __launch_bounds__(1024, 4) void nu1a_kernel(
    const float* __restrict__ h, const float* __restrict__ Wtop,
    const float* __restrict__ bn1_l, float* __restrict__ tmp, int V)
{
  extern __shared__ float lds[];
  float* ldsW = lds;
  float* ldsU = lds + 16384;
  int tid = threadIdx.x;
  stage_w128(Wtop, ldsW, tid);
  __syncthreads();
  const int wave = tid >> 6, lane = tid & 63;
  float* myU = ldsU + wave*1024;
  const int sw = (lane & 7) << 2;
  const float b_a = bn1_l[lane], b_b = bn1_l[lane+64];
  const int gw = blockIdx.x*16 + wave;
  const int nw = gridDim.x*16;
  const int ntiles = V >> 3;
  for (int tt = gw; tt < ntiles; tt += nw) {
    int vb = tt << 3;
    #pragma unroll
    for (int n = 0; n < 8; ++n) {
      myU[n*128 + lane]      = h[(size_t)(vb+n)*HID + lane];
      myU[n*128 + lane + 64] = h[(size_t)(vb+n)*HID + lane + 64];
    }
    float aa[8], ab[8];
    #pragma unroll
    for (int n = 0; n < 8; ++n) { aa[n] = 0.f; ab[n] = 0.f; }
    #pragma unroll 8
    for (int k0 = 0; k0 < 128; k0 += 4) {
      int kk = k0 ^ sw;
      float4 wA = *(const float4*)&ldsW[lane*128 + kk];
      float4 wB = *(const float4*)&ldsW[(lane+64)*128 + kk];
      #pragma unroll
      for (int n = 0; n < 8; ++n) {
        float4 u = *(const float4*)&myU[n*128 + k0];
        dot4(aa[n], u, wA); dot4(ab[n], u, wB);
      }
    }
    #pragma unroll
    for (int n = 0; n < 8; ++n) {
      tmp[(size_t)(vb+n)*HID + lane]      = aa[n] + b_a;
      tmp[(size_t)(vb+n)*HID + lane + 64] = ab[n] + b_b;
    }
  }
}

__global__ __launch_bounds__(1024, 4) void nu1b_kernel(
    const float* __restrict__ tmp, const float* __restrict__ agg,
    const float* __restrict__ Wbot, float* __restrict__ q, int V)
{
  extern __shared__ float lds[];
  float* ldsW = lds;
  float* ldsU = lds + 16384;
  int tid = threadIdx.x;
  stage_w128(Wbot, ldsW, tid);
  __syncthreads();
  const int wave = tid >> 6, lane = tid & 63;
  float* myU = ldsU + wave*1024;
  const int sw = (lane & 7) << 2;
  const int gw = blockIdx.x*16 + wave;
  const int nw = gridDim.x*16;
  const int ntiles = V >> 3;
  for (int tt = gw; tt < ntiles; tt += nw) {
    int vb = tt << 3;
    #pragma unroll
    for (int n = 0; n < 8; ++n) {
      myU[n*128 + lane]      = agg[(size_t)(vb+n)*HID + lane];
      myU[n*128 + lane + 64] = agg[(size_t)(vb+n)*HID + lane + 64];
    }
    float aa[8], ab[8];
    #pragma unroll
    for (int n = 0; n < 8; ++n) { aa[n] = 0.f; ab[n] = 0.f; }
    #pragma unroll 8
    for (int k0 = 0; k0 < 128; k0 += 4) {
      int kk = k0 ^ sw;
      float4 wA = *(const float4*)&ldsW[lane*128 + kk];
      float4 wB = *(const float4*)&ldsW[(lane+64)*128 + kk];
      #pragma unroll
      for (int n = 0; n < 8; ++n) {
        float4 u = *(const float4*)&myU[n*128 + k0];
        dot4(aa[n], u, wA); dot4(ab[n], u, wB);
      }
    }
    #pragma unroll
    for (int n = 0; n < 8; ++n) {
      q[(size_t)(vb+n)*HID + lane]      = silu_f(aa[n] + tmp[(size_t)(vb+n)*HID + lane]);
      q[(size_t)(vb+n)*HID + lane + 64] = silu_f(ab[n] + tmp[(size_t)(vb+n)*HID + lane + 64]);
    }
  }
}

__global__ __launch_bounds__(1024, 4) void nu2_kernel(
    const float* __restrict__ q, const float* __restrict__ Wn2_l,
    const float* __restrict__ bn2_l, float* __restrict__ h, int V)
{
  extern __shared__ float lds[];
  float* ldsW = lds;
  float* ldsU = lds + 16384;
  int tid = threadIdx.x;
  stage_w128(Wn2_l, ldsW, tid);
  __syncthreads();
  const int wave = tid >> 6, lane = tid & 63;
  float* myU = ldsU + wave*1024;
  const int sw = (lane & 7) << 2;
  const float b_a = bn2_l[lane], b_b = bn2_l[lane+64];
  const int gw = blockIdx.x*16 + wave;
  const int nw = gridDim.x*16;
  const int ntiles = V >> 3;
  for (int tt = gw; tt < ntiles; tt += nw) {
    int vb = tt << 3;
    #pragma unroll
    for (int n = 0; n < 8; ++n) {
      myU[n*128 + lane]      = q[(size_t)(vb+n)*HID + lane];
      myU[n*128 + lane + 64] = q[(size_t)(vb+n)*HID + lane + 64];
    }
    float aa[8], ab[8];
    #pragma unroll
    for (int n = 0; n < 8; ++n) { aa[n] = 0.f; ab[n] = 0.f; }
    #pragma unroll 8
    for (int k0 = 0; k0 < 128; k0 += 4) {
      int kk = k0 ^ sw;
      float4 wA = *(const float4*)&ldsW[lane*128 + kk];
      float4 wB = *(const float4*)&ldsW[(lane+64)*128 + kk];
      #pragma unroll
      for (int n = 0; n < 8; ++n) {
        float4 u = *(const float4*)&myU[n*128 + k0];
        dot4(aa[n], u, wA); dot4(ab[n], u, wB);
      }
    }
    #pragma unroll
    for (int n = 0; n < 8; ++n) {
      h[(size_t)(vb+n)*HID + lane]      += aa[n] + b_a;
      h[(size_t)(vb+n)*HID + lane + 64] += ab[n] + b_b;
    }
  }
}

__global__ void vel_kernel(const float4* __restrict__ x4, const float* __restrict__ pos,
                           float* __restrict__ out, int V) {
  int v = blockIdx.x * blockDim.x + threadIdx.x;
  if (v < V) {
    float4 xv = x4[v];
    out[3*v]   = xv.x - pos[3*v];
    out[3*v+1] = xv.y - pos[3*v+1];
    out[3*v+2] = xv.z - pos[3*v+2];
  }
}

extern "C" void kernel_launch(void* const* d_in, const int* in_sizes, int n_in,
                              void* d_out, int out_size, void* d_ws, size_t ws_size,
                              hipStream_t stream) {
  const float* pos   = (const float*)d_in[0];
  const float* t     = (const float*)d_in[1];
  const float* z     = (const float*)d_in[2];
  const int*   ei    = (const int*)d_in[3];
  const int*   batch = (const int*)d_in[4];
  const float* te_w1 = (const float*)d_in[5];
  const float* te_b1 = (const float*)d_in[6];
  const float* te_w2 = (const float*)d_in[7];
  const float* te_b2 = (const float*)d_in[8];
  const float* cp_w  = (const float*)d_in[9];
  const float* cp_b  = (const float*)d_in[10];
  const float* We1   = (const float*)d_in[11];
  const float* be1   = (const float*)d_in[12];
  const float* We2   = (const float*)d_in[13];
  const float* be2   = (const float*)d_in[14];
  const float* Wc1   = (const float*)d_in[15];
  const float* bc1   = (const float*)d_in[16];
  const float* Wc2   = (const float*)d_in[17];
  const float* Wn1   = (const float*)d_in[18];
  const float* bn1   = (const float*)d_in[19];
  const float* Wn2   = (const float*)d_in[20];
  const float* bn2   = (const float*)d_in[21];

  const int V = in_sizes[4];
  const int E = in_sizes[3] / 2;
  const int* rowp = ei;
  const int* colp = ei + E;

  char* base = (char*)d_ws;
  size_t off_b = 0;
  auto alloc = [&](size_t bytes) -> char* {
    char* p = base + off_b;
    off_b += (bytes + 255) & ~(size_t)255;
    return p;
  };
  float*  h     = (float*) alloc((size_t)V*HID*4);
  float*  pA    = (float*) alloc((size_t)V*HID*4);   // p1, later nu1a tmp
  float*  pB    = (float*) alloc((size_t)V*HID*4);   // p2, later agg
  float4* x4    = (float4*)alloc((size_t)V*16);
  char*   m_buf = alloc((size_t)E*HID*4);            // m pairs (uint), later q (float)
  float4* rc_ws = (float4*)alloc((size_t)E*16);
  float*  hb    = (float*) alloc(8*HID*4);
  int*    cnt   = (int*)   alloc((size_t)V*4);
  int*    offp  = (int*)   alloc((size_t)(V+1)*4);
  int*    fill  = (int*)   alloc((size_t)V*4);
  int*    perm  = (int*)   alloc((size_t)E*4);
  unsigned short* wfrag = (unsigned short*)alloc(4*2*32768*sizeof(unsigned short));
  (void)ws_size; (void)n_in; (void)out_size;

  unsigned int* m_pairs = (unsigned int*)m_buf;
  float* q_buf = (float*)m_buf;

  const int DLDS = 131072;
  hipFuncSetAttribute((const void*)phalf_kernel, hipFuncAttributeMaxDynamicSharedMemorySize, DLDS);
  hipFuncSetAttribute((const void*)edge1_kernel, hipFuncAttributeMaxDynamicSharedMemorySize, DLDS);
  hipFuncSetAttribute((const void*)edge2_kernel, hipFuncAttributeMaxDynamicSharedMemorySize, 65536);
  hipFuncSetAttribute((const void*)nu1a_kernel,  hipFuncAttributeMaxDynamicSharedMemorySize, DLDS);
  hipFuncSetAttribute((const void*)nu1b_kernel,  hipFuncAttributeMaxDynamicSharedMemorySize, DLDS);
  hipFuncSetAttribute((const void*)nu2_kernel,   hipFuncAttributeMaxDynamicSharedMemorySize, DLDS);

  hb_kernel<<<8, 128, 0, stream>>>(t, z, te_w1, te_b1, te_w2, te_b2, cp_w, cp_b, hb);
  scatter_h_kernel<<<(V*32 + 255)/256, 256, 0, stream>>>(batch, hb, h, V);
  packx_kernel<<<(V + 255)/256, 256, 0, stream>>>(pos, x4, V);
  hipMemsetAsync(cnt, 0, (size_t)V*4, stream);
  hipMemsetAsync(fill, 0, (size_t)V*4, stream);
  hist_kernel<<<(E + 255)/256, 256, 0, stream>>>(rowp, cnt, E);
  scan_kernel<<<1, 1024, 0, stream>>>(cnt, offp, V);
  scatter_perm_kernel<<<(E + 255)/256, 256, 0, stream>>>(rowp, offp, fill, perm, E);

  // prep MFMA B-fragment streams for We2, Wc1 (hi/lo), all layers
  for (int l = 0; l < NLAY; ++l) {
    wprep_kernel<<<64, 256, 0, stream>>>(We2 + (size_t)l*HID*HID, wfrag + (size_t)(l*2+0)*32768);
    wprep_kernel<<<64, 256, 0, stream>>>(Wc1 + (size_t)l*HID*HID, wfrag + (size_t)(l*2+1)*32768);
  }

  for (int l = 0; l < NLAY; ++l) {
    const float* We1_l = We1 + (size_t)l*257*HID;
    const float* wd2_l = We1_l + 256*HID;
    const float* Wc2_l = Wc2 + (size_t)l*HID;
    const float* Wn1_l = Wn1 + (size_t)l*256*HID;
    const float* Wn2_l = Wn2 + (size_t)l*HID*HID;
    const float* be1_l = be1 + l*HID;
    const float* be2_l = be2 + l*HID;
    const float* bc1_l = bc1 + l*HID;
    const float* bn1_l = bn1 + l*HID;
    const float* bn2_l = bn2 + l*HID;

    phalf_kernel<<<256, 1024, DLDS, stream>>>(h, We1_l, pA, V);
    phalf_kernel<<<256, 1024, DLDS, stream>>>(h, We1_l + 128*HID, pB, V);
    edge1_kernel<<<256, 256, DLDS, stream>>>(rowp, colp, x4, pA, pB,
                                             wfrag + (size_t)(l*2+0)*32768,
                                             wd2_l, be1_l, be2_l, m_pairs, rc_ws, E);
    edge2_kernel<<<512, 512, 65536, stream>>>(wfrag + (size_t)(l*2+1)*32768,
                                              bc1_l, Wc2_l, m_pairs, rc_ws, E);
    agg_kernel<<<(V + 3)/4, 256, 0, stream>>>(offp, perm, m_pairs, rc_ws, pB, x4, V);
    nu1a_kernel<<<256, 1024, DLDS, stream>>>(h, Wn1_l, bn1_l, pA, V);
    nu1b_kernel<<<256, 1024, DLDS, stream>>>(pA, pB, Wn1_l + 128*HID, q_buf, V);
    nu2_kernel<<<256, 1024, DLDS, stream>>>(q_buf, Wn2_l, bn2_l, h, V);
  }
  vel_kernel<<<(V + 255)/256, 256, 0, stream>>>(x4, pos, (float*)d_out, V);
}